// Round 5
// baseline (742.188 us; speedup 1.0000x reference)
//
#include <hip/hip_runtime.h>
#include <cstdint>

#define NROWS 8192
#define FDIM  512

typedef __attribute__((ext_vector_type(8))) unsigned short u16x8;
typedef __attribute__((ext_vector_type(8))) __bf16 bf16x8;
typedef __attribute__((ext_vector_type(4))) float f32x4;

__device__ __forceinline__ unsigned short f2bf(float f) {
    unsigned u = __float_as_uint(f);
    u += 0x7fffu + ((u >> 16) & 1u);   // RNE; inputs are finite/normal
    return (unsigned short)(u >> 16);
}

__device__ __forceinline__ float bf2f(unsigned short h) {
    return __uint_as_float((unsigned)h << 16);
}

__device__ __forceinline__ void gload16(const void* g, void* l) {
    __builtin_amdgcn_global_load_lds(
        (__attribute__((address_space(1))) unsigned int*)g,
        (__attribute__((address_space(3))) unsigned int*)l,
        16, 0, 0);
}

// Software grid barrier (capture-safe; NO cooperative launch needed).
// Safe because 160 KiB LDS forces 1 block/CU and grid == 256 == #CUs, so all
// blocks are co-resident by resource limits. bar[0]=count, bar[1]=generation,
// zeroed via hipMemsetAsync before launch (in-stream, graph-capturable).
__device__ __forceinline__ void grid_sync_sw(unsigned* bar) {
    __syncthreads();
    if (threadIdx.x == 0) {
        __threadfence();   // prior writes visible device-wide
        const unsigned g = __hip_atomic_load(&bar[1], __ATOMIC_ACQUIRE,
                                             __HIP_MEMORY_SCOPE_AGENT);
        const unsigned a = __hip_atomic_fetch_add(&bar[0], 1u, __ATOMIC_ACQ_REL,
                                                  __HIP_MEMORY_SCOPE_AGENT);
        if (a == gridDim.x - 1) {
            __hip_atomic_store(&bar[0], 0u, __ATOMIC_RELAXED,
                               __HIP_MEMORY_SCOPE_AGENT);
            __hip_atomic_fetch_add(&bar[1], 1u, __ATOMIC_RELEASE,
                                   __HIP_MEMORY_SCOPE_AGENT);   // release: cnt reset ordered before
        } else {
            while (__hip_atomic_load(&bar[1], __ATOMIC_ACQUIRE,
                                     __HIP_MEMORY_SCOPE_AGENT) == g)
                __builtin_amdgcn_s_sleep(8);
        }
        __threadfence();
    }
    __syncthreads();
}

#define G8_BAR()     __builtin_amdgcn_s_barrier()
#define G8_WAITV(N)  asm volatile("s_waitcnt vmcnt(" #N ")" ::: "memory")

// gemm512 staging/read/mfma macros (r3-verified)
#define G5_STAGE_A(DST, KK)                                                     \
    _Pragma("unroll") for (int j = 0; j < 2; ++j) {                             \
        const int r = w * 16 + j * 8;                                           \
        gload16(&A[(size_t)(i0 + r + lsub) * lda + (KK) + kof], (DST) + r * 64); }

#define G5_STAGE_B(BB, DST, KK)                                                 \
    _Pragma("unroll") for (int j = 0; j < 2; ++j) {                             \
        const int r16 = w * 16 + j * 8;                                         \
        const int n = ((r16 >> 5) * 128) + (BB) * 32 + (r16 & 31);              \
        gload16(&B[(size_t)(n + lsub) * ldb + (KK) + kof], (DST) + n * 64); }

#define G5_READ_A(ASL)                                                          \
    _Pragma("unroll") for (int mt = 0; mt < 4; ++mt)                            \
    _Pragma("unroll") for (int ks = 0; ks < 2; ++ks) {                          \
        const int row_ = wr * 64 + mt * 16 + lrow;                              \
        af[mt][ks] = __builtin_bit_cast(bf16x8,                                 \
            *(const u16x8*)&(ASL)[row_ * 64 + ((ks * 32 + quad * 8) ^ ((lrow & 7) * 8))]); }

#define G5_READ_B(P, BSL)                                                       \
    _Pragma("unroll") for (int ntp = 0; ntp < 2; ++ntp)                         \
    _Pragma("unroll") for (int ks = 0; ks < 2; ++ks) {                          \
        const int n_ = wc * 128 + ((P) * 2 + ntp) * 16 + lrow;                  \
        bfr[ntp][ks] = __builtin_bit_cast(bf16x8,                               \
            *(const u16x8*)&(BSL)[n_ * 64 + ((ks * 32 + quad * 8) ^ ((lrow & 7) * 8))]); }

#define G5_MFMA(P)                                                              \
    __builtin_amdgcn_s_setprio(1);                                              \
    _Pragma("unroll") for (int mt = 0; mt < 4; ++mt)                            \
    _Pragma("unroll") for (int ntp = 0; ntp < 2; ++ntp)                         \
    _Pragma("unroll") for (int ks = 0; ks < 2; ++ks)                            \
        acc[mt][(P) * 2 + ntp] = __builtin_amdgcn_mfma_f32_16x16x32_bf16(       \
            af[mt][ks], bfr[ntp][ks], acc[mt][(P) * 2 + ntp], 0, 0, 0);         \
    __builtin_amdgcn_s_setprio(0);

// ===========================================================================
// MEGA kernel: entire pipeline, grid = 256 blocks (1/CU by LDS) x 512 threads,
// 160 KiB dynamic LDS, phases separated by software grid barriers. 256-thread
// phases run as 2 virtual half-blocks; barrier counts uniform across halves.
// All math identical to the r3-verified kernels (same fp32 accumulation
// order), so absmax must match r3 exactly.
// ===========================================================================
__global__ __launch_bounds__(512, 2) void mega_kernel(
    const float* __restrict__ graph, const float* __restrict__ x,
    const float* __restrict__ weight, const float* __restrict__ bias,
    float* __restrict__ out,
    unsigned short* __restrict__ gT, unsigned short* __restrict__ xsT,
    unsigned short* __restrict__ wT, unsigned short* __restrict__ Tb,
    float* __restrict__ deg, float* __restrict__ P,
    float* __restrict__ dpart, unsigned* __restrict__ bar) {
    extern __shared__ unsigned short sh[];
    const int bid  = blockIdx.x;      // 0..255
    const int t    = threadIdx.x;     // 0..511
    const int half = t >> 8;          // 0/1 -> virtual 256-thread block
    const int th   = t & 255;

    // ---- Phase T: transpose graph -> gT bf16, + dpart column partials -----
    {   // per-half LDS: float tile[128][65] (33280 B) at byte {0, 81920}
        float* tile = (float*)((char*)sh + half * 81920);
        const int ci = th & 15, ir = th >> 4;
        #pragma unroll 1
        for (int it = 0; it < 16; ++it) {
            const int vt = it * 512 + bid * 2 + half;    // 0..8191, exact
            const int i0 = (vt & 127) * 64;
            const int j0 = (vt >> 7) * 128;
            {   // coalesced float4 reads
                const int c4 = ci * 4;
                #pragma unroll
                for (int p = 0; p < 8; ++p) {
                    const int rr = ir + p * 16;          // 0..127
                    const float4 v = *(const float4*)&graph[(size_t)(j0 + rr) * NROWS + i0 + c4];
                    tile[rr * 65 + c4 + 0] = v.x; tile[rr * 65 + c4 + 1] = v.y;
                    tile[rr * 65 + c4 + 2] = v.z; tile[rr * 65 + c4 + 3] = v.w;
                }
            }
            __syncthreads();
            {   // ushort8 stores + column sums
                float cs[4];
                #pragma unroll
                for (int p = 0; p < 4; ++p) {
                    const int i = ir + p * 16;           // 0..63
                    u16x8 o; float c = 0.f;
                    #pragma unroll
                    for (int q = 0; q < 8; ++q) {
                        const float v = tile[(ci * 8 + q) * 65 + i];
                        o[q] = f2bf(v);
                        c += v;
                    }
                    *(u16x8*)&gT[(size_t)(i0 + i) * NROWS + j0 + ci * 8] = o;
                    cs[p] = c;
                }
                #pragma unroll
                for (int p = 0; p < 4; ++p) {
                    float c = cs[p];
                    #pragma unroll
                    for (int off = 1; off < 16; off <<= 1) c += __shfl_xor(c, off);
                    if (ci == 0)
                        dpart[(size_t)(vt >> 7) * NROWS + i0 + ir + p * 16] = c;
                }
            }
            __syncthreads();   // tile reused next iteration
        }
    }
    grid_sync_sw(bar);

    // ---- Phase D: deg[i] = sum over 64 j-block partials (deterministic) ---
    {
        const int i = bid * 512 + t;
        if (i < NROWS) {
            float s = 0.f;
            #pragma unroll
            for (int jb = 0; jb < 64; ++jb) s += dpart[(size_t)jb * NROWS + i];
            deg[i] = s;
        }
    }
    grid_sync_sw(bar);

    // ---- Phase S: xsT = (d^-1/2 x)^T bf16 (1024 tiles), wT = W^T (64) -----
    {   // per-half LDS: float tile[64][65] + drow[64] at byte {0, 81920}
        float* tileS = (float*)((char*)sh + half * 81920);
        float* drowS = tileS + 64 * 65;
        #pragma unroll 1
        for (int it = 0; it < 3; ++it) {
            const int vt = it * 512 + bid * 2 + half;
            const bool active = vt < 1088;
            const bool isw = vt >= 1024;
            const int vv = isw ? vt - 1024 : vt;
            const float* src = isw ? weight : x;
            unsigned short* dst = isw ? wT : xsT;
            const int rows = isw ? FDIM : NROWS;
            const int c0 = (vv & 7) * 64;
            const int r0 = (vv >> 3) * 64;
            if (active && th < 64) drowS[th] = isw ? 1.0f : rsqrtf(deg[r0 + th]);
            __syncthreads();
            if (active) {
                const int c4 = (th & 15) * 4;
                const int r  = th >> 4;
                #pragma unroll
                for (int p = 0; p < 4; ++p) {
                    const int rr = r + p * 16;
                    const float4 v = *(const float4*)&src[(size_t)(r0 + rr) * FDIM + c0 + c4];
                    const float s = drowS[rr];
                    tileS[rr * 65 + c4 + 0] = v.x * s; tileS[rr * 65 + c4 + 1] = v.y * s;
                    tileS[rr * 65 + c4 + 2] = v.z * s; tileS[rr * 65 + c4 + 3] = v.w * s;
                }
            }
            __syncthreads();
            if (active) {
                const int jj  = (th & 15) * 4;
                const int c2b = th >> 4;
                #pragma unroll
                for (int p = 0; p < 4; ++p) {
                    const int c2 = c2b + p * 16;
                    ushort4 o;
                    o.x = f2bf(tileS[(jj + 0) * 65 + c2]);
                    o.y = f2bf(tileS[(jj + 1) * 65 + c2]);
                    o.z = f2bf(tileS[(jj + 2) * 65 + c2]);
                    o.w = f2bf(tileS[(jj + 3) * 65 + c2]);
                    *(ushort4*)&dst[(size_t)(c0 + c2) * rows + r0 + jj] = o;
                }
            }
            __syncthreads();
        }
    }
    grid_sync_sw(bar);

    // ---- Phase G1: T-partials = gT @ xsT  (r3-verified gemm512 body) ------
    {
        const unsigned short* A = gT;  const unsigned short* B = xsT;
        const int lda = NROWS, ldb = NROWS;
        const int klen = NROWS / 4;                  // split-K = 4
        const int bx = bid & 63, bz = bid >> 6;
        const int i0 = bx * 128;
        const int kbeg = bz * klen;
        const int w    = t >> 6, lane = t & 63;
        const int wr   = w >> 2, wc = w & 3;         // 2x4 wave grid
        const int lrow = lane & 15, quad = lane >> 4;
        const int lsub = lane >> 3, kq = lane & 7;
        const int kof  = (kq * 8) ^ (lsub * 8);      // source-side swizzle
        unsigned short* Asl0 = sh;                   // 2 x 8192 u16
        unsigned short* Bsl0 = sh + 16384;           // 2 x 32768 u16

        f32x4  acc[4][8] = {};
        bf16x8 af[4][2], bfr[2][2];

        G5_STAGE_A(Asl0, kbeg);
        G5_STAGE_B(0, Bsl0, kbeg);
        G5_STAGE_B(1, Bsl0, kbeg);
        G5_STAGE_B(2, Bsl0, kbeg);
        G5_STAGE_B(3, Bsl0, kbeg);
        G8_WAITV(6); G8_BAR();                       // A,S0 landed

        const int NT = klen >> 6;
        for (int tt = 0; tt < NT - 1; ++tt) {
            const int s = tt & 1;
            unsigned short* Asl  = Asl0 + s * 8192;
            unsigned short* Bsl  = Bsl0 + s * 32768;
            unsigned short* AslN = Asl0 + (s ^ 1) * 8192;
            unsigned short* BslN = Bsl0 + (s ^ 1) * 32768;
            const int kn = kbeg + (tt + 1) * 64;
            G5_READ_A(Asl); G5_READ_B(0, Bsl);
            G5_STAGE_A(AslN, kn); G5_STAGE_B(0, BslN, kn);
            G8_BAR(); G5_MFMA(0); G8_WAITV(8); G8_BAR();
            G5_READ_B(1, Bsl); G5_STAGE_B(1, BslN, kn);
            G8_BAR(); G5_MFMA(1); G8_WAITV(8); G8_BAR();
            G5_READ_B(2, Bsl); G5_STAGE_B(2, BslN, kn);
            G8_BAR(); G5_MFMA(2); G8_WAITV(8); G8_BAR();
            G5_READ_B(3, Bsl); G5_STAGE_B(3, BslN, kn);
            G8_BAR(); G5_MFMA(3); G8_WAITV(6); G8_BAR();
        }
        {   // tail tile
            const int s = (NT - 1) & 1;
            unsigned short* Asl = Asl0 + s * 8192;
            unsigned short* Bsl = Bsl0 + s * 32768;
            G5_READ_A(Asl); G5_READ_B(0, Bsl);
            G8_BAR(); G5_MFMA(0); G8_WAITV(4); G8_BAR();
            G5_READ_B(1, Bsl);
            G8_BAR(); G5_MFMA(1); G8_WAITV(2); G8_BAR();
            G5_READ_B(2, Bsl);
            G8_BAR(); G5_MFMA(2); G8_WAITV(0); G8_BAR();
            G5_READ_B(3, Bsl);
            G8_BAR(); G5_MFMA(3);
        }
        float* __restrict__ Co = P + (size_t)bz * ((size_t)NROWS * FDIM);
        #pragma unroll
        for (int mt = 0; mt < 4; ++mt) {
            #pragma unroll
            for (int nt = 0; nt < 8; ++nt) {
                const int col = wc * 128 + nt * 16 + lrow;
                #pragma unroll
                for (int r = 0; r < 4; ++r) {
                    const int row = i0 + wr * 64 + mt * 16 + quad * 4 + r;
                    Co[(size_t)row * FDIM + col] = acc[mt][nt][r];
                }
            }
        }
    }
    grid_sync_sw(bar);

    // ---- Phase R4: Tb = bf16(sum of 4 split-K partials) -------------------
    {
        const float4* Pf = (const float4*)P;
        const size_t stride = (size_t)NROWS * FDIM / 4;
        #pragma unroll 1
        for (int pass = 0; pass < 2; ++pass) {
            const int vb = pass * 512 + bid * 2 + half;   // 0..1023, exact
            #pragma unroll
            for (int p = 0; p < 4; ++p) {
                const size_t idx = (size_t)vb * 1024 + p * 256 + th;
                const float4 a  = Pf[idx];
                const float4 b2 = Pf[idx + stride];
                const float4 c2 = Pf[idx + 2 * stride];
                const float4 d2 = Pf[idx + 3 * stride];
                ushort4 o;
                o.x = f2bf(a.x + b2.x + c2.x + d2.x);
                o.y = f2bf(a.y + b2.y + c2.y + d2.y);
                o.z = f2bf(a.z + b2.z + c2.z + d2.z);
                o.w = f2bf(a.w + b2.w + c2.w + d2.w);
                *(ushort4*)&Tb[idx * 4] = o;
            }
        }
    }
    grid_sync_sw(bar);

    // ---- Phase G2: out = d^-1/2 (Tb @ wT) + bias  (legacy m97 body) -------
    {   // 512 virtual 256-thread blocks = 2 halves x 256 blocks, exact
        const int vb = bid * 2 + half;               // 0..511
        const int bx = vb & 63, by = vb >> 6;        // m-block, n-block
        unsigned short* As2 = sh + half * 40960;     // per-half 80 KiB region
        unsigned short* Bs2 = As2 + 8192;
        const int w4   = th >> 6, lane = th & 63;
        const int wr   = w4 >> 1, wc = w4 & 1;
        const int lrow = lane & 15, quad = lane >> 4;
        const int i0 = bx * 128, f0 = by * 64;
        f32x4 acc2[4][2] = {};

        for (int k0 = 0; k0 < FDIM; k0 += 64) {
            #pragma unroll
            for (int i = 0; i < 4; ++i) {            // A: 1024 x 16B chunks
                const int q  = th + i * 256;
                const int ks = q >> 9, rem = q & 511;
                const int m  = rem >> 2, kq2 = rem & 3;
                gload16(&Tb[(size_t)(i0 + m) * FDIM + k0 + ks * 32 + kq2 * 8],
                        &As2[(size_t)(w4 * 64 + i * 256) * 8]);
            }
            #pragma unroll
            for (int i = 0; i < 2; ++i) {            // B: 512 x 16B chunks
                const int q  = th + i * 256;
                const int ks = q >> 8, rem = q & 255;
                const int n  = rem >> 2, kq2 = rem & 3;
                gload16(&wT[(size_t)(f0 + n) * FDIM + k0 + ks * 32 + kq2 * 8],
                        &Bs2[(size_t)(w4 * 64 + i * 256) * 8]);
            }
            __syncthreads();
            #pragma unroll
            for (int ks = 0; ks < 2; ++ks) {
                bf16x8 af2[4], bfr2[2];
                #pragma unroll
                for (int mt = 0; mt < 4; ++mt)
                    af2[mt] = __builtin_bit_cast(bf16x8,
                        *(const u16x8*)&As2[ks * 4096 + (wr * 64 + mt * 16 + lrow) * 32 + quad * 8]);
                #pragma unroll
                for (int nt = 0; nt < 2; ++nt)
                    bfr2[nt] = __builtin_bit_cast(bf16x8,
                        *(const u16x8*)&Bs2[ks * 2048 + (wc * 32 + nt * 16 + lrow) * 32 + quad * 8]);
                #pragma unroll
                for (int mt = 0; mt < 4; ++mt)
                    #pragma unroll
                    for (int nt = 0; nt < 2; ++nt)
                        acc2[mt][nt] = __builtin_amdgcn_mfma_f32_16x16x32_bf16(
                            af2[mt], bfr2[nt], acc2[mt][nt], 0, 0, 0);
            }
            __syncthreads();
        }
        #pragma unroll
        for (int mt = 0; mt < 4; ++mt) {
            #pragma unroll
            for (int nt = 0; nt < 2; ++nt) {
                const int col = f0 + wc * 32 + nt * 16 + lrow;
                #pragma unroll
                for (int r = 0; r < 4; ++r) {
                    const int row = i0 + wr * 64 + mt * 16 + quad * 4 + r;
                    const float dsc = rsqrtf(deg[row]);
                    out[(size_t)row * FDIM + col] = dsc * acc2[mt][nt][r] + bias[col];
                }
            }
        }
    }
}

// ===========================================================================
// Fallback path: the r3-verified multi-kernel sequence (kept verbatim).
// ===========================================================================
__global__ __launch_bounds__(256) void transpose_bf16_kernel(
    const float* __restrict__ graph, unsigned short* __restrict__ gT,
    float* __restrict__ dpart) {
    __shared__ float tile[128][65];
    const int t  = threadIdx.x;
    const int i0 = blockIdx.x * 64;
    const int j0 = blockIdx.y * 128;
    {
        const int c4 = (t & 15) * 4;
        const int r  = t >> 4;
        #pragma unroll
        for (int p = 0; p < 8; ++p) {
            const int rr = r + p * 16;
            const float4 v = *(const float4*)&graph[(size_t)(j0 + rr) * NROWS + i0 + c4];
            tile[rr][c4 + 0] = v.x; tile[rr][c4 + 1] = v.y;
            tile[rr][c4 + 2] = v.z; tile[rr][c4 + 3] = v.w;
        }
    }
    __syncthreads();
    {
        const int ci = t & 15;
        const int ir = t >> 4;
        float cs[4];
        #pragma unroll
        for (int p = 0; p < 4; ++p) {
            const int i = ir + p * 16;
            u16x8 o; float c = 0.f;
            #pragma unroll
            for (int q = 0; q < 8; ++q) {
                const float v = tile[ci * 8 + q][i];
                o[q] = f2bf(v);
                c += v;
            }
            *(u16x8*)&gT[(size_t)(i0 + i) * NROWS + j0 + ci * 8] = o;
            cs[p] = c;
        }
        #pragma unroll
        for (int p = 0; p < 4; ++p) {
            float c = cs[p];
            #pragma unroll
            for (int off = 1; off < 16; off <<= 1) c += __shfl_xor(c, off);
            if (ci == 0)
                dpart[(size_t)blockIdx.y * NROWS + i0 + ir + p * 16] = c;
        }
    }
}

__global__ __launch_bounds__(256) void deg_reduce_kernel(
    const float* __restrict__ dpart, float* __restrict__ deg) {
    const int i = blockIdx.x * 256 + threadIdx.x;
    float s = 0.f;
    #pragma unroll
    for (int jb = 0; jb < 64; ++jb) s += dpart[(size_t)jb * NROWS + i];
    deg[i] = s;
}

__global__ __launch_bounds__(256) void transpose_scale_kernel(
    const float* __restrict__ src, unsigned short* __restrict__ dst,
    int rows, int cols, const float* __restrict__ degv) {
    __shared__ float tile[64][65];
    __shared__ float drow[64];
    const int t  = threadIdx.x;
    const int c0 = blockIdx.x * 64;
    const int r0 = blockIdx.y * 64;
    if (t < 64) drow[t] = degv ? rsqrtf(degv[r0 + t]) : 1.0f;
    __syncthreads();
    {
        const int c4 = (t & 15) * 4;
        const int r  = t >> 4;
        #pragma unroll
        for (int p = 0; p < 4; ++p) {
            const int rr = r + p * 16;
            const float4 v = *(const float4*)&src[(size_t)(r0 + rr) * cols + c0 + c4];
            const float s = drow[rr];
            tile[rr][c4 + 0] = v.x * s; tile[rr][c4 + 1] = v.y * s;
            tile[rr][c4 + 2] = v.z * s; tile[rr][c4 + 3] = v.w * s;
        }
    }
    __syncthreads();
    {
        const int jj  = (t & 15) * 4;
        const int c2b = t >> 4;
        #pragma unroll
        for (int p = 0; p < 4; ++p) {
            const int c2 = c2b + p * 16;
            ushort4 o;
            o.x = f2bf(tile[jj + 0][c2]);
            o.y = f2bf(tile[jj + 1][c2]);
            o.z = f2bf(tile[jj + 2][c2]);
            o.w = f2bf(tile[jj + 3][c2]);
            *(ushort4*)&dst[(size_t)(c0 + c2) * rows + r0 + jj] = o;
        }
    }
}

template <int BN, int MODE>
__global__ __launch_bounds__(256) void gemm_nt_kernel(
    const unsigned short* __restrict__ A, const unsigned short* __restrict__ B,
    int klen, int lda, int ldb, float* __restrict__ Cf, size_t zstride,
    const float* __restrict__ degv, const float* __restrict__ bias, int ldc) {
    __shared__ unsigned short As[2 * 128 * 32];
    __shared__ unsigned short Bs[2 * BN * 32];
    constexpr int NF = BN / 32;
    const int nx = gridDim.x, ny = gridDim.y;
    const int flat = blockIdx.x + nx * (blockIdx.y + ny * blockIdx.z);
    const int swz  = (flat & 7) * ((nx * ny * (int)gridDim.z) >> 3) + (flat >> 3);
    const int bx = swz % nx, by = (swz / nx) % ny, bz = swz / (nx * ny);
    const int t    = threadIdx.x;
    const int w    = t >> 6, lane = t & 63;
    const int wr   = w >> 1, wc = w & 1;
    const int lrow = lane & 15, quad = lane >> 4;
    const int i0   = bx * 128, f0 = by * BN;
    const int kbeg = bz * klen;
    f32x4 acc[4][NF] = {};

    for (int k0 = kbeg; k0 < kbeg + klen; k0 += 64) {
        #pragma unroll
        for (int i = 0; i < 4; ++i) {
            const int q  = t + i * 256;
            const int ks = q >> 9, rem = q & 511;
            const int m  = rem >> 2, kq = rem & 3;
            gload16(&A[(size_t)(i0 + m) * lda + k0 + ks * 32 + kq * 8],
                    &As[(size_t)(w * 64 + i * 256) * 8]);
        }
        #pragma unroll
        for (int i = 0; i < BN / 32; ++i) {
            const int q  = t + i * 256;
            const int ks = q / (BN * 4), rem = q % (BN * 4);
            const int n  = rem >> 2, kq = rem & 3;
            gload16(&B[(size_t)(f0 + n) * ldb + k0 + ks * 32 + kq * 8],
                    &Bs[(size_t)(w * 64 + i * 256) * 8]);
        }
        __syncthreads();
        #pragma unroll
        for (int ks = 0; ks < 2; ++ks) {
            bf16x8 af[4], bfr[NF];
            #pragma unroll
            for (int mt = 0; mt < 4; ++mt)
                af[mt] = __builtin_bit_cast(bf16x8,
                    *(const u16x8*)&As[ks * 4096 + (wr * 64 + mt * 16 + lrow) * 32 + quad * 8]);
            #pragma unroll
            for (int nt = 0; nt < NF; ++nt)
                bfr[nt] = __builtin_bit_cast(bf16x8,
                    *(const u16x8*)&Bs[ks * (BN * 32) + (wc * (BN / 2) + nt * 16 + lrow) * 32 + quad * 8]);
            #pragma unroll
            for (int mt = 0; mt < 4; ++mt)
                #pragma unroll
                for (int nt = 0; nt < NF; ++nt)
                    acc[mt][nt] = __builtin_amdgcn_mfma_f32_16x16x32_bf16(
                        af[mt], bfr[nt], acc[mt][nt], 0, 0, 0);
        }
        __syncthreads();
    }
    float* __restrict__ Co = Cf + (size_t)bz * zstride;
    #pragma unroll
    for (int mt = 0; mt < 4; ++mt) {
        #pragma unroll
        for (int nt = 0; nt < NF; ++nt) {
            const int col = f0 + wc * (BN / 2) + nt * 16 + lrow;
            #pragma unroll
            for (int r = 0; r < 4; ++r) {
                const int row = i0 + wr * 64 + mt * 16 + quad * 4 + r;
                if (MODE == 1) {
                    const float dsc = rsqrtf(degv[row]);
                    Co[(size_t)row * ldc + col] = dsc * acc[mt][nt][r] + bias[col];
                } else {
                    Co[(size_t)row * ldc + col] = acc[mt][nt][r];
                }
            }
        }
    }
}

__global__ __launch_bounds__(512, 2) void gemm512_kernel(
    const unsigned short* __restrict__ A, const unsigned short* __restrict__ B,
    int klen, int lda, int ldb, float* __restrict__ Cf, size_t zstride, int ldc) {
    extern __shared__ unsigned short sh[];
    const int i0   = blockIdx.x * 128;
    const int kbeg = blockIdx.z * klen;
    const int t    = threadIdx.x;
    const int w    = t >> 6, lane = t & 63;
    const int wr   = w >> 2, wc = w & 3;
    const int lrow = lane & 15, quad = lane >> 4;
    const int lsub = lane >> 3, kq = lane & 7;
    const int kof  = (kq * 8) ^ (lsub * 8);

    unsigned short* Asl0 = sh;
    unsigned short* Bsl0 = sh + 16384;

    f32x4  acc[4][8] = {};
    bf16x8 af[4][2], bfr[2][2];

    G5_STAGE_A(Asl0, kbeg);
    G5_STAGE_B(0, Bsl0, kbeg);
    G5_STAGE_B(1, Bsl0, kbeg);
    G5_STAGE_B(2, Bsl0, kbeg);
    G5_STAGE_B(3, Bsl0, kbeg);
    G8_WAITV(6); G8_BAR();

    const int NT = klen >> 6;
    for (int tt = 0; tt < NT - 1; ++tt) {
        const int s = tt & 1;
        unsigned short* Asl  = Asl0 + s * 8192;
        unsigned short* Bsl  = Bsl0 + s * 32768;
        unsigned short* AslN = Asl0 + (s ^ 1) * 8192;
        unsigned short* BslN = Bsl0 + (s ^ 1) * 32768;
        const int kn = kbeg + (tt + 1) * 64;
        G5_READ_A(Asl); G5_READ_B(0, Bsl);
        G5_STAGE_A(AslN, kn); G5_STAGE_B(0, BslN, kn);
        G8_BAR(); G5_MFMA(0); G8_WAITV(8); G8_BAR();
        G5_READ_B(1, Bsl); G5_STAGE_B(1, BslN, kn);
        G8_BAR(); G5_MFMA(1); G8_WAITV(8); G8_BAR();
        G5_READ_B(2, Bsl); G5_STAGE_B(2, BslN, kn);
        G8_BAR(); G5_MFMA(2); G8_WAITV(8); G8_BAR();
        G5_READ_B(3, Bsl); G5_STAGE_B(3, BslN, kn);
        G8_BAR(); G5_MFMA(3); G8_WAITV(6); G8_BAR();
    }
    {
        const int s = (NT - 1) & 1;
        unsigned short* Asl = Asl0 + s * 8192;
        unsigned short* Bsl = Bsl0 + s * 32768;
        G5_READ_A(Asl); G5_READ_B(0, Bsl);
        G8_BAR(); G5_MFMA(0); G8_WAITV(4); G8_BAR();
        G5_READ_B(1, Bsl);
        G8_BAR(); G5_MFMA(1); G8_WAITV(2); G8_BAR();
        G5_READ_B(2, Bsl);
        G8_BAR(); G5_MFMA(2); G8_WAITV(0); G8_BAR();
        G5_READ_B(3, Bsl);
        G8_BAR(); G5_MFMA(3);
    }

    float* __restrict__ Co = Cf + (size_t)blockIdx.z * zstride;
    #pragma unroll
    for (int mt = 0; mt < 4; ++mt) {
        #pragma unroll
        for (int nt = 0; nt < 8; ++nt) {
            const int col = wc * 128 + nt * 16 + lrow;
            #pragma unroll
            for (int r = 0; r < 4; ++r) {
                const int row = i0 + wr * 64 + mt * 16 + quad * 4 + r;
                Co[(size_t)row * ldc + col] = acc[mt][nt][r];
            }
        }
    }
}

__global__ __launch_bounds__(256) void reduce4_kernel(
    const float4* __restrict__ P, unsigned short* __restrict__ Tb) {
    const size_t stride = (size_t)NROWS * FDIM / 4;
    #pragma unroll
    for (int p = 0; p < 4; ++p) {
        const size_t idx = (size_t)blockIdx.x * 1024 + p * 256 + threadIdx.x;
        const float4 a = P[idx];
        const float4 b = P[idx + stride];
        const float4 c = P[idx + 2 * stride];
        const float4 d = P[idx + 3 * stride];
        ushort4 o;
        o.x = f2bf(a.x + b.x + c.x + d.x);
        o.y = f2bf(a.y + b.y + c.y + d.y);
        o.z = f2bf(a.z + b.z + c.z + d.z);
        o.w = f2bf(a.w + b.w + c.w + d.w);
        *(ushort4*)&Tb[idx * 4] = o;
    }
}

extern "C" void kernel_launch(void* const* d_in, const int* in_sizes, int n_in,
                              void* d_out, int out_size, void* d_ws, size_t ws_size,
                              hipStream_t stream) {
    const float* x      = (const float*)d_in[0];
    const float* graph  = (const float*)d_in[1];
    const float* weight = (const float*)d_in[2];
    const float* bias   = (const float*)d_in[3];
    float* out = (float*)d_out;

    char* ws = (char*)d_ws;
    const size_t GT_B  = (size_t)NROWS * NROWS * 2;    // 134.2 MB
    const size_t XST_B = (size_t)FDIM * NROWS * 2;     // 8.4 MB
    const size_t WT_B  = (size_t)FDIM * FDIM * 2;      // 0.5 MB
    const size_t TB_B  = (size_t)NROWS * FDIM * 2;     // 8.4 MB
    const size_t P_B   = (size_t)NROWS * FDIM * 4 * 4; // 64 MB
    const size_t DP_B  = (size_t)64 * NROWS * 4;       // 2 MB
    unsigned short* gT  = (unsigned short*)(ws);
    unsigned short* xsT = (unsigned short*)(ws + GT_B);
    unsigned short* wT  = (unsigned short*)(ws + GT_B + XST_B);
    unsigned short* Tb  = (unsigned short*)(ws + GT_B + XST_B + WT_B);
    float* deg          = (float*)(ws + GT_B + XST_B + WT_B + TB_B);
    float* P            = (float*)(ws + GT_B + XST_B + WT_B + TB_B + 32768);
    float* dpart        = (float*)(ws + GT_B + XST_B + WT_B + TB_B + 32768 + P_B);
    unsigned* bar       = (unsigned*)(ws + GT_B + XST_B + WT_B + TB_B + 32768 + P_B + DP_B);

    // ---- Primary: single persistent mega-kernel, software grid barrier ----
    // (plain launch -> graph-capture-safe; NO hipLaunchCooperativeKernel)
    hipError_t aerr = hipFuncSetAttribute((const void*)mega_kernel,
        hipFuncAttributeMaxDynamicSharedMemorySize, 163840);
    bool useMega = (aerr == hipSuccess);
    if (useMega) {
        hipMemsetAsync(bar, 0, 64, stream);   // zero barrier count+generation
        hipLaunchKernelGGL(mega_kernel, dim3(256), dim3(512), 163840, stream,
                           graph, x, weight, bias, out,
                           gT, xsT, wT, Tb, deg, P, dpart, bar);
        useMega = (hipGetLastError() == hipSuccess);
    }
    if (useMega) return;

    // ---- Fallback: r3-verified multi-kernel sequence ----------------------
    hipLaunchKernelGGL(transpose_bf16_kernel, dim3(NROWS / 64, NROWS / 128), dim3(256), 0, stream,
                       graph, gT, dpart);
    hipLaunchKernelGGL(deg_reduce_kernel, dim3(NROWS / 256), dim3(256), 0, stream, dpart, deg);
    hipLaunchKernelGGL(transpose_scale_kernel, dim3(FDIM / 64, NROWS / 64), dim3(256), 0, stream,
                       x, xsT, NROWS, FDIM, deg);
    hipLaunchKernelGGL(transpose_scale_kernel, dim3(FDIM / 64, FDIM / 64), dim3(256), 0, stream,
                       weight, wT, FDIM, FDIM, (const float*)nullptr);
    hipError_t gerr = hipFuncSetAttribute((const void*)gemm512_kernel,
        hipFuncAttributeMaxDynamicSharedMemorySize, 163840);
    bool useG5 = (gerr == hipSuccess);
    if (useG5) {
        hipLaunchKernelGGL(gemm512_kernel, dim3(NROWS / 128, 1, 4), dim3(512), 163840, stream,
                           gT, xsT, NROWS / 4, NROWS, NROWS, P, (size_t)NROWS * FDIM, FDIM);
        useG5 = (hipGetLastError() == hipSuccess);
    }
    if (!useG5) {
        hipLaunchKernelGGL((gemm_nt_kernel<128, 2>), dim3(NROWS / 128, FDIM / 128, 4), dim3(256), 0, stream,
                           gT, xsT, NROWS / 4, NROWS, NROWS, P, (size_t)NROWS * FDIM,
                           (const float*)nullptr, (const float*)nullptr, FDIM);
    }
    hipLaunchKernelGGL(reduce4_kernel, dim3(NROWS * FDIM / 4096), dim3(256), 0, stream,
                       (const float4*)P, Tb);
    hipLaunchKernelGGL((gemm_nt_kernel<64, 1>), dim3(NROWS / 128, FDIM / 64, 1), dim3(256), 0, stream,
                       Tb, wT, FDIM, FDIM, FDIM, out, (size_t)0,
                       deg, bias, FDIM);
}